// Round 2
// baseline (130.304 us; speedup 1.0000x reference)
//
#include <hip/hip_runtime.h>
#include <hip/hip_bf16.h>
#include <hip/hip_fp16.h>

#define NB 16
#define CCH 64
#define LL 4096   // 64*64
#define DD 1024   // 32*32

typedef _Float16 h8 __attribute__((ext_vector_type(8)));
typedef _Float16 h4 __attribute__((ext_vector_type(4)));
typedef _Float16 h2 __attribute__((ext_vector_type(2)));
typedef float    f4v __attribute__((ext_vector_type(4)));

#if defined(__has_builtin)
#if __has_builtin(__builtin_amdgcn_exp2f)
#define EXP2F(x) __builtin_amdgcn_exp2f(x)
#endif
#endif
#ifndef EXP2F
#define EXP2F(x) exp2f(x)
#endif

#define MFMA16(a, b, c) __builtin_amdgcn_mfma_f32_16x16x32_f16((a), (b), (c), 0, 0, 0)

// ---------------------------------------------------------------------------
// Kernel 1: MFMA-GEMM prep (exact R9 version — best measured ~18 µs).
// out[px][o] = sum_c x[c][px] * wall[o][c]; o: 0-7 theta (log2e-scaled),
// 8-15 phi, 16-47 g. Block = 4 waves = 64-px tile; grid = N*64 = 1024.
// ---------------------------------------------------------------------------
__global__ __launch_bounds__(256, 6) void prep_kernel(
    const float* __restrict__ x,        // [N, 64, 4096]
    const float* __restrict__ w_theta,  // [8, 64]
    const float* __restrict__ w_phi,    // [8, 64]
    const float* __restrict__ w_g,      // [32, 64]
    _Float16* __restrict__ theta_out,   // [N, 4096, 8]  (pre-scaled by log2e)
    _Float16* __restrict__ phi_out,     // [N, 1024, 8]
    _Float16* __restrict__ gT_out)      // [N, 32, 1024]
{
    __shared__ __align__(16) float smem[64 * 68];   // 17.4 KB
    float* xs   = smem;        // [64 ch][68] f32 (px stride 68)
    float* pool = smem;        // [64 px][49] f32 (aliases xs after barrier)

    const int n    = blockIdx.x >> 6;
    const int rem  = blockIdx.x & 63;
    const int rg   = rem >> 1;          // row-pair 0..31 (rows 2rg, 2rg+1)
    const int half = rem & 1;           // column half (32 cols)
    const int tid  = threadIdx.x;
    const int w    = tid >> 6;          // wave = M-tile 0..3
    const int lane = tid & 63;
    const int m16  = lane & 15;
    const int quad = lane >> 4;

    // ---- B-frags from weights: B[k = kc*32 + quad*8 + j][o = t*16 + m16]
    h8 bf[3][2];
#pragma unroll
    for (int t = 0; t < 3; ++t) {
        const float* row;
        float scale = 1.0f;
        if (t == 0) {
            if (m16 < 8) { row = w_theta + m16 * 64; scale = 1.44269504f; }
            else         { row = w_phi + (m16 - 8) * 64; }
        } else if (t == 1) {
            row = w_g + m16 * 64;
        } else {
            row = w_g + (16 + m16) * 64;
        }
#pragma unroll
        for (int kc = 0; kc < 2; ++kc) {
            const float* p = row + kc * 32 + quad * 8;
            float4 a = *(const float4*)p;
            float4 b = *(const float4*)(p + 4);
            bf[t][kc][0] = (_Float16)(a.x * scale);
            bf[t][kc][1] = (_Float16)(a.y * scale);
            bf[t][kc][2] = (_Float16)(a.z * scale);
            bf[t][kc][3] = (_Float16)(a.w * scale);
            bf[t][kc][4] = (_Float16)(b.x * scale);
            bf[t][kc][5] = (_Float16)(b.y * scale);
            bf[t][kc][6] = (_Float16)(b.z * scale);
            bf[t][kc][7] = (_Float16)(b.w * scale);
        }
    }

    // ---- stage x tile: 64 ch x 64 px, float4 loads -> ds_write_b128 ----
    {
        const int ch = tid >> 2;
        const int s  = tid & 3;
        const float* xc = x + (size_t)n * CCH * LL + (size_t)ch * LL;
        float4 vv[4];
#pragma unroll
        for (int i = 0; i < 4; ++i) {
            const int f    = i * 4 + s;
            const int row  = f >> 3;
            const int colg = f & 7;
            const int l    = (rg * 2 + row) * 64 + half * 32 + colg * 4;
            vv[i] = *(const float4*)(xc + l);
        }
#pragma unroll
        for (int i = 0; i < 4; ++i) {
            const int f    = i * 4 + s;
            const int row  = f >> 3;
            const int colg = f & 7;
            *(float4*)(xs + ch * 68 + row * 32 + colg * 4) = vv[i];
        }
    }
    __syncthreads();

    // ---- A-frags: A[m = w*16 + m16][k = kc*32 + quad*8 + j] from xs ----
    h8 af[2];
#pragma unroll
    for (int kc = 0; kc < 2; ++kc) {
#pragma unroll
        for (int j = 0; j < 8; ++j) {
            float v = xs[(kc * 32 + quad * 8 + j) * 68 + w * 16 + m16];
            af[kc][j] = (_Float16)v;
        }
    }

    // ---- 6 MFMAs: 3 N-tiles x 2 K-chunks ----
    f4v cfr[3];
#pragma unroll
    for (int t = 0; t < 3; ++t) {
        f4v c = {0.f, 0.f, 0.f, 0.f};
        c = MFMA16(af[0], bf[t][0], c);
        c = MFMA16(af[1], bf[t][1], c);
        cfr[t] = c;
    }
    __syncthreads();   // all xs reads done -> pool may alias

    // ---- C -> pool[px][o]: D row = quad*4+r (px-local), col = m16
    {
#pragma unroll
        for (int t = 0; t < 3; ++t) {
#pragma unroll
            for (int r = 0; r < 4; ++r)
                pool[(w * 16 + quad * 4 + r) * 49 + t * 16 + m16] = cfr[t][r];
        }
    }
    __syncthreads();

    // ---- theta store: one thread per px, h8
    if (tid < 64) {
        const int px  = tid;
        const int row = px >> 5, col = px & 31;
        const int l   = (rg * 2 + row) * 64 + half * 32 + col;
        const float* pr = pool + px * 49;
        h8 tv;
#pragma unroll
        for (int k = 0; k < 8; ++k) tv[k] = (_Float16)pr[k];
        *(h8*)(theta_out + ((size_t)n * LL + l) * 8) = tv;
    }

    // ---- 2x2 maxpool: 16 pooled cols x 40 features
    const int d_base = rg * 32 + half * 16;
    for (int idx = tid; idx < 640; idx += 256) {
        const int f40 = idx >> 4;       // 0..7 phi, 8..39 g
        const int pc  = idx & 15;
        const int fcol = 8 + f40;
        float v = fmaxf(fmaxf(pool[(2 * pc) * 49 + fcol],      pool[(2 * pc + 1) * 49 + fcol]),
                        fmaxf(pool[(32 + 2 * pc) * 49 + fcol], pool[(33 + 2 * pc) * 49 + fcol]));
        const int d = d_base + pc;
        if (f40 < 8) phi_out[((size_t)n * DD + d) * 8 + f40] = (_Float16)v;
        else         gT_out[((size_t)n * 32 + (f40 - 8)) * DD + d] = (_Float16)v;
    }
}

// ---------------------------------------------------------------------------
// Kernel 2: attn, R12: QK^T moved onto MFMA (S^T = phi·theta^T, K=8 padded
// into K=32: only quad 0 carries real A/B data, quads 1-3 are zero so they
// contribute nothing). S^T C layout (col = q = m16, row = d = quad*4+r)
// puts each lane's exp-scores exactly where the PV A-frag wants them,
// provided the gT B-frag k<->d map is permuted to
//   k = quad*8+j  <->  d = d0 + (j<4 ? quad*4+j : 16+quad*4+(j-4)).
// Eliminates all 512 fdot2/thread and 48 of 64 ds_read_b128/thread.
// phi_s is now UNPADDED [1024][8] f16 (quad0-only reads, 2-way = free).
// Epilogue (ssum reduce, red combine, w_o proj, residual store) unchanged.
// ---------------------------------------------------------------------------
__global__ __launch_bounds__(256, 8) void attn_kernel(
    const float*    __restrict__ x,       // [N, 64, 4096]
    const _Float16* __restrict__ theta,   // [N, 4096, 8]
    const _Float16* __restrict__ phi,     // [N, 1024, 8]
    const _Float16* __restrict__ gT,      // [N, 32, 1024]
    const float*    __restrict__ w_o,     // [64, 32]
    const float*    __restrict__ gamma_p, // scalar
    float*          __restrict__ out)     // [N, 64, 4096]
{
    // phi_s: [1024][8] f16 = 16384 B (unpadded).
    // red [4][32][37] f32 = 18944 B aliases phi_s; ssum at +18944 (512 B);
    // out_s [32][68] f32 = 8704 B aliases red after the combine barrier.
    __shared__ __align__(16) char smem[18944 + 512];
    _Float16* phi_s  = (_Float16*)smem;
    float*    red    = (float*)smem;                // [4][32][37]
    float*    out_s  = (float*)smem;                // [32][68]
    float*    ssum_s = (float*)(smem + 18944);      // [4][32]

    const int n    = blockIdx.x >> 7;
    const int lblk = blockIdx.x & 127;
    const int tid  = threadIdx.x;
    const int h    = tid >> 6;            // D-quarter 0..3 (one per wave)
    const int lane = tid & 63;
    const int m16  = lane & 15;
    const int quad = lane >> 4;
    const int l0   = lblk * 32;           // block query base (32 q)

    const _Float16* gT_n = gT + (size_t)n * 32 * DD;

    // stage full phi[n] into LDS, plain layout [d][8]
    {
        const float4* ps = (const float4*)(phi + (size_t)n * DD * 8);
        float4* pd = (float4*)phi_s;
#pragma unroll
        for (int i = 0; i < 4; ++i) {
            const int d = tid + 256 * i;
            pd[d] = ps[d];
        }
    }

    // theta rows for this block's two 16-q M-tiles
    h8 th0 = *(const h8*)(theta + ((size_t)n * LL + l0 + m16) * 8);
    h8 th1 = *(const h8*)(theta + ((size_t)n * LL + l0 + 16 + m16) * 8);

    // S^T B-frags: B[k=quad*8+j][n=q=m16] = theta[q][k]; real k<8 -> quad 0
    const h8 zero8 = {};
    h8 bq0 = (quad == 0) ? th0 : zero8;
    h8 bq1 = (quad == 0) ? th1 : zero8;

    // w_o B-frags for this wave's och-pair: och = m16 + 16*(vp*2+i)
    const int vp = h >> 1;
    h8 wof[2];
#pragma unroll
    for (int i = 0; i < 2; ++i) {
        const float* wr = w_o + (size_t)(m16 + 16 * (vp * 2 + i)) * 32 + quad * 8;
        float4 wa = *(const float4*)wr;
        float4 wb = *(const float4*)(wr + 4);
        wof[i][0] = (_Float16)wa.x; wof[i][1] = (_Float16)wa.y;
        wof[i][2] = (_Float16)wa.z; wof[i][3] = (_Float16)wa.w;
        wof[i][4] = (_Float16)wb.x; wof[i][5] = (_Float16)wb.y;
        wof[i][6] = (_Float16)wb.z; wof[i][7] = (_Float16)wb.w;
    }

    __syncthreads();   // phi_s ready

    f4v c00 = {0.f, 0.f, 0.f, 0.f}, c01 = c00, c10 = c00, c11 = c00;
    float ssum0 = 0.f, ssum1 = 0.f;

    // per-lane bases
    const _Float16* gq0 = gT_n + (size_t)m16 * DD + h * 256;        // ch-tile 0
    const _Float16* gq1 = gT_n + (size_t)(16 + m16) * DD + h * 256; // ch-tile 1
    const _Float16* ph_base = phi_s + (size_t)(h * 256 + m16) * 8;  // quad0 rows

#pragma unroll 2
    for (int c = 0; c < 8; ++c) {
        const int d0 = c * 32;

        // phi A-frags for d-tiles t0/t1: A[m=d_local=m16][k=quad*8+j];
        // real k<8 -> only quad 0 loads, others stay zero.
        h8 ap0 = zero8, ap1 = zero8;
        if (quad == 0) {
            ap0 = *(const h8*)(ph_base + d0 * 8);
            ap1 = *(const h8*)(ph_base + (d0 + 16) * 8);
        }

        // gT B-frags with the permuted k<->d map (2 x b64 per ch-tile)
        h4 b0lo = *(const h4*)(gq0 + d0 + quad * 4);
        h4 b0hi = *(const h4*)(gq0 + d0 + 16 + quad * 4);
        h4 b1lo = *(const h4*)(gq1 + d0 + quad * 4);
        h4 b1hi = *(const h4*)(gq1 + d0 + 16 + quad * 4);
        h8 b0 = __builtin_shufflevector(b0lo, b0hi, 0, 1, 2, 3, 4, 5, 6, 7);
        h8 b1 = __builtin_shufflevector(b1lo, b1hi, 0, 1, 2, 3, 4, 5, 6, 7);

        const f4v z4 = {0.f, 0.f, 0.f, 0.f};

        // ---- q-tile 0: scores -> exp -> PV A-frag
        f4v s00 = MFMA16(ap0, bq0, z4);   // d-tile0 x q-tile0
        f4v s10 = MFMA16(ap1, bq0, z4);   // d-tile1 x q-tile0
        h8 a0;
#pragma unroll
        for (int r = 0; r < 4; ++r) {
            float e0 = EXP2F(s00[r]); ssum0 += e0; a0[r]     = (_Float16)e0;
            float f0 = EXP2F(s10[r]); ssum0 += f0; a0[4 + r] = (_Float16)f0;
        }

        // ---- q-tile 1
        f4v s01 = MFMA16(ap0, bq1, z4);
        f4v s11 = MFMA16(ap1, bq1, z4);
        h8 a1;
#pragma unroll
        for (int r = 0; r < 4; ++r) {
            float e1 = EXP2F(s01[r]); ssum1 += e1; a1[r]     = (_Float16)e1;
            float f1 = EXP2F(s11[r]); ssum1 += f1; a1[4 + r] = (_Float16)f1;
        }

        // ---- PV accumulate (same layout as R9)
        c00 = MFMA16(a0, b0, c00);
        c01 = MFMA16(a0, b1, c01);
        c10 = MFMA16(a1, b0, c10);
        c11 = MFMA16(a1, b1, c11);
    }

    // quarter-D softmax denominators (quads hold disjoint d)
    ssum0 += __shfl_xor(ssum0, 16); ssum0 += __shfl_xor(ssum0, 32);
    ssum1 += __shfl_xor(ssum1, 16); ssum1 += __shfl_xor(ssum1, 32);
    if (quad == 0) {
        ssum_s[h * 32 + m16]      = ssum0;   // beyond phi_s use: safe now
        ssum_s[h * 32 + 16 + m16] = ssum1;
    }
    __syncthreads();   // ALL waves done reading phi_s -> red may alias it

    // write partial C (C layout: row q = quad*4+r, col ch = m16) into red
    {
        float* rg = red + (size_t)h * 32 * 37;
#pragma unroll
        for (int r = 0; r < 4; ++r) {
            const int rr = quad * 4 + r;
            rg[rr * 37 + m16]             = c00[r];
            rg[rr * 37 + 16 + m16]        = c01[r];
            rg[(16 + rr) * 37 + m16]      = c10[r];
            rg[(16 + rr) * 37 + 16 + m16] = c11[r];
        }
    }
    __syncthreads();

    // combine 4 quarters + normalize + pack A-frag.
    // wave h projects M-tile t = h&1: q = t*16 + m16, k = gch = quad*8+j
    const int t = h & 1;
    h8 pa;
    {
        const int q = t * 16 + m16;
        const float* rq = red + q * 37 + quad * 8;
        float ss = ssum_s[q] + ssum_s[32 + q] + ssum_s[64 + q] + ssum_s[96 + q];
        float inv = 1.0f / ss;
#pragma unroll
        for (int j = 0; j < 8; ++j) {
            float sv = rq[j] + rq[32 * 37 + j] + rq[64 * 37 + j] + rq[96 * 37 + j];
            pa[j] = (_Float16)(sv * inv);
        }
    }
    __syncthreads();   // everyone done reading red -> safe to alias out_s

    // projection: D[row = local q = quad*4+r][col = och], q = t*16 + quad*4+r
    const f4v zero = {0.f, 0.f, 0.f, 0.f};
#pragma unroll
    for (int i = 0; i < 2; ++i) {
        f4v pv = MFMA16(pa, wof[i], zero);
        const int och = m16 + 16 * (vp * 2 + i);
        float* od = out_s + (size_t)(t * 16 + quad * 4) * 68 + och;
#pragma unroll
        for (int r = 0; r < 4; ++r) od[r * 68] = pv[r];
    }
    __syncthreads();

    // coalesced store + residual: thread -> och = tid>>2, 8 q from (tid&3)*8
    const float gamma = gamma_p[0];
    const int soch = tid >> 2;
    const int qoff = (tid & 3) * 8;
    const float* xrow = x   + (size_t)n * CCH * LL + (size_t)soch * LL + l0 + qoff;
    float*       orow = out + (size_t)n * CCH * LL + (size_t)soch * LL + l0 + qoff;
#pragma unroll
    for (int i = 0; i < 2; ++i) {
        float4 xv = *(const float4*)(xrow + i * 4);
        float4 ov;
        ov.x = xv.x + gamma * out_s[(qoff + i * 4)     * 68 + soch];
        ov.y = xv.y + gamma * out_s[(qoff + i * 4 + 1) * 68 + soch];
        ov.z = xv.z + gamma * out_s[(qoff + i * 4 + 2) * 68 + soch];
        ov.w = xv.w + gamma * out_s[(qoff + i * 4 + 3) * 68 + soch];
        *(float4*)(orow + i * 4) = ov;
    }
}

// ---------------------------------------------------------------------------
extern "C" void kernel_launch(void* const* d_in, const int* in_sizes, int n_in,
                              void* d_out, int out_size, void* d_ws, size_t ws_size,
                              hipStream_t stream) {
    const float* x       = (const float*)d_in[0];
    const float* w_theta = (const float*)d_in[1];
    const float* w_phi   = (const float*)d_in[2];
    const float* w_g     = (const float*)d_in[3];
    const float* w_o     = (const float*)d_in[4];
    const float* gamma   = (const float*)d_in[5];
    float* out = (float*)d_out;

    // ws layout (f16): theta 1 MB | phi 256 KB | gT 1 MB
    _Float16* theta_h = (_Float16*)d_ws;                    // N*L*8
    _Float16* phi_h   = theta_h + (size_t)NB * LL * 8;      // N*D*8
    _Float16* gT_h    = phi_h   + (size_t)NB * DD * 8;      // N*32*D

    prep_kernel<<<1024, 256, 0, stream>>>(x, w_theta, w_phi, w_g,
                                          theta_h, phi_h, gT_h);
    attn_kernel<<<2048, 256, 0, stream>>>(x, theta_h, phi_h, gT_h,
                                          w_o, gamma, out);
}